// Round 1
// baseline (3537.403 us; speedup 1.0000x reference)
//
#include <hip/hip_runtime.h>
#include <hip/hip_bf16.h>

// HeteroGNN: 2x (shared-weight 4-relation GCNConv + graph LayerNorm)
// Strategy: merge 4 relations into one 6.4M edge list; build dst-CSR once
// (counting sort); aggregate with one wave per dst node (64 lanes x float4
// = 256 channels) -> no float atomics; fuse global sum/sumsq into agg kernel.

#define RELS 4
#define HDIM 256

struct EdgePtrs {
    const int*   ei[RELS];
    const float* ew[RELS];
};

// ---------------- CSR build ----------------

__global__ __launch_bounds__(256) void count_kernel(EdgePtrs ep, int* __restrict__ cnts, int E) {
    int bpr = gridDim.x >> 2;            // blocks per relation
    int rel = blockIdx.x / bpr;
    int e = (blockIdx.x - rel * bpr) * 256 + threadIdx.x;
    if (e < E) {
        int dst = ep.ei[rel][E + e];
        atomicAdd(&cnts[dst], 1);
    }
}

// exclusive scan, 1024 elements per block (256 threads x 4)
__global__ __launch_bounds__(256) void scan_kernel(const int* __restrict__ in, int* __restrict__ out,
                                                   int* __restrict__ blockSums, int n) {
    __shared__ int wsum[4];
    int t = threadIdx.x;
    int base = blockIdx.x * 1024;
    int idx0 = base + t * 4;
    int v[4];
#pragma unroll
    for (int j = 0; j < 4; ++j) v[j] = (idx0 + j < n) ? in[idx0 + j] : 0;
    int local = v[0] + v[1] + v[2] + v[3];
    int lane = t & 63;
    int incl = local;
#pragma unroll
    for (int off = 1; off < 64; off <<= 1) {
        int y = __shfl_up(incl, off, 64);
        if (lane >= off) incl += y;
    }
    int waveId = t >> 6;
    if (lane == 63) wsum[waveId] = incl;
    __syncthreads();
    int waveOff = 0;
    for (int wi = 0; wi < waveId; ++wi) waveOff += wsum[wi];
    int run = waveOff + incl - local;   // exclusive prefix for this thread's 4
#pragma unroll
    for (int j = 0; j < 4; ++j) {
        if (idx0 + j < n) out[idx0 + j] = run;
        run += v[j];
    }
    if (t == 255) blockSums[blockIdx.x] = waveOff + incl;
}

__global__ __launch_bounds__(256) void add_off_kernel(int* __restrict__ offs, const int* __restrict__ bsums,
                                                      int* __restrict__ cursor, int n) {
    int i = blockIdx.x * 256 + threadIdx.x;
    if (i < n) {
        int o = offs[i] + bsums[i >> 10];
        offs[i] = o;
        cursor[i] = o;
    }
}

__global__ __launch_bounds__(256) void fill_kernel(EdgePtrs ep, int* __restrict__ cursor,
                                                   int* __restrict__ esrc, float* __restrict__ eww, int E) {
    int bpr = gridDim.x >> 2;
    int rel = blockIdx.x / bpr;
    int e = (blockIdx.x - rel * bpr) * 256 + threadIdx.x;
    if (e < E) {
        int src = ep.ei[rel][e];
        int dst = ep.ei[rel][E + e];
        float w = ep.ew[rel][e];
        int pos = atomicAdd(&cursor[dst], 1);
        esrc[pos] = src;
        eww[pos] = w;
    }
}

// ---------------- GEMM: [M,K] x [K,256] -> [M,256] ----------------

template <int K>
__global__ __launch_bounds__(256) void gemm_kernel(const float* __restrict__ A, const float* __restrict__ W,
                                                   float* __restrict__ out, int M) {
    __shared__ float At[32 * K];
    int rowBase = blockIdx.x * 32;
    int t = threadIdx.x;
    for (int idx = t; idx < 32 * K; idx += 256) {
        int r = idx / K;
        int k = idx & (K - 1);
        int row = rowBase + r;
        At[idx] = (row < M) ? A[(size_t)row * K + k] : 0.f;
    }
    __syncthreads();
    float acc[32];
#pragma unroll
    for (int r = 0; r < 32; ++r) acc[r] = 0.f;
    int col = t;
    for (int k = 0; k < K; k += 4) {
        float w0 = W[(k + 0) * HDIM + col];
        float w1 = W[(k + 1) * HDIM + col];
        float w2 = W[(k + 2) * HDIM + col];
        float w3 = W[(k + 3) * HDIM + col];
#pragma unroll
        for (int r = 0; r < 32; ++r) {
            float4 a = *(const float4*)&At[r * K + k];
            acc[r] += a.x * w0 + a.y * w1 + a.z * w2 + a.w * w3;
        }
    }
#pragma unroll
    for (int r = 0; r < 32; ++r) {
        int row = rowBase + r;
        if (row < M) out[(size_t)row * HDIM + col] = acc[r];
    }
}

// ---------------- Aggregation: one wave per dst node ----------------

__global__ __launch_bounds__(256) void agg_kernel(const float* __restrict__ Hf, const int* __restrict__ offs,
                                                  const int* __restrict__ cnts, const int* __restrict__ esrc,
                                                  const float* __restrict__ eww, const float* __restrict__ bias,
                                                  float* __restrict__ outp, float* __restrict__ stats, int nNodes) {
    int gwave = (blockIdx.x << 2) | (threadIdx.x >> 6);
    int lane = threadIdx.x & 63;
    int c = lane << 2;
    float4 acc = make_float4(0.f, 0.f, 0.f, 0.f);
    if (gwave < nNodes) {
        acc = *(const float4*)&bias[c];
        int start = __builtin_amdgcn_readfirstlane(offs[gwave]);
        int cnt = __builtin_amdgcn_readfirstlane(cnts[gwave]);
        const int* sp = esrc + start;
        const float* wp = eww + start;
        int i = 0;
        for (; i + 4 <= cnt; i += 4) {
            int s0 = sp[i], s1 = sp[i + 1], s2 = sp[i + 2], s3 = sp[i + 3];
            float w0 = wp[i], w1 = wp[i + 1], w2 = wp[i + 2], w3 = wp[i + 3];
            float4 v0 = *(const float4*)&Hf[((size_t)s0 << 8) + c];
            float4 v1 = *(const float4*)&Hf[((size_t)s1 << 8) + c];
            float4 v2 = *(const float4*)&Hf[((size_t)s2 << 8) + c];
            float4 v3 = *(const float4*)&Hf[((size_t)s3 << 8) + c];
            acc.x += w0 * v0.x + w1 * v1.x + w2 * v2.x + w3 * v3.x;
            acc.y += w0 * v0.y + w1 * v1.y + w2 * v2.y + w3 * v3.y;
            acc.z += w0 * v0.z + w1 * v1.z + w2 * v2.z + w3 * v3.z;
            acc.w += w0 * v0.w + w1 * v1.w + w2 * v2.w + w3 * v3.w;
        }
        for (; i < cnt; ++i) {
            int s = sp[i];
            float w = wp[i];
            float4 v = *(const float4*)&Hf[((size_t)s << 8) + c];
            acc.x += w * v.x;
            acc.y += w * v.y;
            acc.z += w * v.z;
            acc.w += w * v.w;
        }
        *(float4*)&outp[((size_t)gwave << 8) + c] = acc;
    }
    // fused global sum / sumsq for graph LayerNorm
    float s = acc.x + acc.y + acc.z + acc.w;
    float ss = acc.x * acc.x + acc.y * acc.y + acc.z * acc.z + acc.w * acc.w;
#pragma unroll
    for (int off = 32; off > 0; off >>= 1) {
        s += __shfl_down(s, off, 64);
        ss += __shfl_down(ss, off, 64);
    }
    __shared__ float ls[8];
    int wid = threadIdx.x >> 6;
    if (lane == 0) { ls[wid] = s; ls[4 + wid] = ss; }
    __syncthreads();
    if (threadIdx.x == 0) {
        atomicAdd(&stats[0], ls[0] + ls[1] + ls[2] + ls[3]);
        atomicAdd(&stats[1], ls[4] + ls[5] + ls[6] + ls[7]);
    }
}

// ---------------- Graph LayerNorm (elementwise, in-place) ----------------

__global__ __launch_bounds__(256) void ln_kernel(float* __restrict__ data, const float* __restrict__ stats,
                                                 const float* __restrict__ lw, const float* __restrict__ lb,
                                                 long long total, float invM) {
    long long i4 = (long long)blockIdx.x * 256 + threadIdx.x;
    long long idx = i4 * 4;
    if (idx >= total) return;
    float m = stats[0] * invM;
    float var = stats[1] * invM - m * m;
    float inv = 1.f / (sqrtf(fmaxf(var, 0.f)) + 1e-5f);
    float4 v = *(float4*)&data[idx];
    int c = (int)(idx & (HDIM - 1));
    float4 w = *(const float4*)&lw[c];
    float4 b = *(const float4*)&lb[c];
    v.x = (v.x - m) * inv * w.x + b.x;
    v.y = (v.y - m) * inv * w.y + b.y;
    v.z = (v.z - m) * inv * w.z + b.z;
    v.w = (v.w - m) * inv * w.w + b.w;
    *(float4*)&data[idx] = v;
}

// ---------------- launch ----------------

extern "C" void kernel_launch(void* const* d_in, const int* in_sizes, int n_in,
                              void* d_out, int out_size, void* d_ws, size_t ws_size,
                              hipStream_t stream) {
    const float* x = (const float*)d_in[0];
    EdgePtrs ep;
    ep.ei[0] = (const int*)d_in[1]; ep.ew[0] = (const float*)d_in[2];
    ep.ei[1] = (const int*)d_in[3]; ep.ew[1] = (const float*)d_in[4];
    ep.ei[2] = (const int*)d_in[5]; ep.ew[2] = (const float*)d_in[6];
    ep.ei[3] = (const int*)d_in[7]; ep.ew[3] = (const float*)d_in[8];
    const float* W1 = (const float*)d_in[9];
    const float* b1 = (const float*)d_in[10];
    const float* W2 = (const float*)d_in[11];
    const float* b2 = (const float*)d_in[12];
    const float* ln1w = (const float*)d_in[13];
    const float* ln1b = (const float*)d_in[14];
    const float* ln2w = (const float*)d_in[15];
    const float* ln2b = (const float*)d_in[16];

    const int N = in_sizes[0] / 128;  // 100000
    const int E = in_sizes[2];        // 1600000
    const size_t totE = (size_t)RELS * E;
    float* out = (float*)d_out;

    // workspace layout
    char* ws = (char*)d_ws;
    float* Hbuf = (float*)ws;                       // N*256 floats (102.4 MB)
    int* esrc = (int*)(Hbuf + (size_t)N * HDIM);    // 4E ints
    float* eww = (float*)(esrc + totE);             // 4E floats
    int* cnts = (int*)(eww + totE);                 // N
    int* offs = cnts + N;                           // N
    int* cursor = offs + N;                         // N
    int* bsums = cursor + N;                        // 1024 (scan scratch)
    float* stats = (float*)(bsums + 1024);          // 4 floats

    hipMemsetAsync(cnts, 0, (size_t)N * sizeof(int), stream);
    hipMemsetAsync(stats, 0, 4 * sizeof(float), stream);

    // CSR build (shared by both layers)
    int bpr = (E + 255) / 256;
    count_kernel<<<RELS * bpr, 256, 0, stream>>>(ep, cnts, E);
    int nb = (N + 1023) / 1024;
    scan_kernel<<<nb, 256, 0, stream>>>(cnts, offs, bsums, N);
    scan_kernel<<<1, 256, 0, stream>>>(bsums, bsums, bsums + 512, nb);
    add_off_kernel<<<(N + 255) / 256, 256, 0, stream>>>(offs, bsums, cursor, N);
    fill_kernel<<<RELS * bpr, 256, 0, stream>>>(ep, cursor, esrc, eww, E);

    long long total = (long long)N * HDIM;
    float invM = 1.f / (float)total;
    int gemmGrid = (N + 31) / 32;
    int aggGrid = (N + 3) / 4;
    int lnGrid = (int)((total / 4 + 255) / 256);

    // Layer 1: x@W1 -> Hbuf ; agg -> d_out (+stats) ; LN in-place on d_out
    gemm_kernel<128><<<gemmGrid, 256, 0, stream>>>(x, W1, Hbuf, N);
    agg_kernel<<<aggGrid, 256, 0, stream>>>(Hbuf, offs, cnts, esrc, eww, b1, out, stats, N);
    ln_kernel<<<lnGrid, 256, 0, stream>>>(out, stats, ln1w, ln1b, total, invM);

    // Layer 2: d_out@W2 -> Hbuf ; agg -> d_out (+stats) ; LN in-place
    gemm_kernel<256><<<gemmGrid, 256, 0, stream>>>(out, W2, Hbuf, N);
    agg_kernel<<<aggGrid, 256, 0, stream>>>(Hbuf, offs, cnts, esrc, eww, b2, out, stats + 2, N);
    ln_kernel<<<lnGrid, 256, 0, stream>>>(out, stats + 2, ln2w, ln2b, total, invM);
}

// Round 2
// 2912.478 us; speedup vs baseline: 1.2146x; 1.2146x over previous
//
#include <hip/hip_runtime.h>
#include <hip/hip_bf16.h>

// HeteroGNN: 2x (shared-weight 4-relation GCNConv + graph LayerNorm)
// R2: Hbuf stored as bf16 (halves gather bytes -- agg is LLC-BW bound at
// ~6.2 TB/s effective); (src,weight) packed int2; LN1 fused into GEMM2's
// A-staging; 8-edge unroll in agg.

#define RELS 4
#define HDIM 256

struct EdgePtrs {
    const int*   ei[RELS];
    const float* ew[RELS];
};

__device__ inline unsigned short f32_to_bf16_rne(float f) {
    unsigned int u = __float_as_uint(f);
    unsigned int r = 0x7FFFu + ((u >> 16) & 1u);
    return (unsigned short)((u + r) >> 16);
}

// ---------------- CSR build ----------------

__global__ __launch_bounds__(256) void count_kernel(EdgePtrs ep, int* __restrict__ cnts, int E) {
    int bpr = gridDim.x >> 2;
    int rel = blockIdx.x / bpr;
    int e = (blockIdx.x - rel * bpr) * 256 + threadIdx.x;
    if (e < E) {
        int dst = ep.ei[rel][E + e];
        atomicAdd(&cnts[dst], 1);
    }
}

__global__ __launch_bounds__(256) void scan_kernel(const int* __restrict__ in, int* __restrict__ out,
                                                   int* __restrict__ blockSums, int n) {
    __shared__ int wsum[4];
    int t = threadIdx.x;
    int base = blockIdx.x * 1024;
    int idx0 = base + t * 4;
    int v[4];
#pragma unroll
    for (int j = 0; j < 4; ++j) v[j] = (idx0 + j < n) ? in[idx0 + j] : 0;
    int local = v[0] + v[1] + v[2] + v[3];
    int lane = t & 63;
    int incl = local;
#pragma unroll
    for (int off = 1; off < 64; off <<= 1) {
        int y = __shfl_up(incl, off, 64);
        if (lane >= off) incl += y;
    }
    int waveId = t >> 6;
    if (lane == 63) wsum[waveId] = incl;
    __syncthreads();
    int waveOff = 0;
    for (int wi = 0; wi < waveId; ++wi) waveOff += wsum[wi];
    int run = waveOff + incl - local;
#pragma unroll
    for (int j = 0; j < 4; ++j) {
        if (idx0 + j < n) out[idx0 + j] = run;
        run += v[j];
    }
    if (t == 255) blockSums[blockIdx.x] = waveOff + incl;
}

__global__ __launch_bounds__(256) void add_off_kernel(int* __restrict__ offs, const int* __restrict__ bsums,
                                                      int* __restrict__ cursor, int n) {
    int i = blockIdx.x * 256 + threadIdx.x;
    if (i < n) {
        int o = offs[i] + bsums[i >> 10];
        offs[i] = o;
        cursor[i] = o;
    }
}

__global__ __launch_bounds__(256) void fill_kernel(EdgePtrs ep, int* __restrict__ cursor,
                                                   int2* __restrict__ epack, int E) {
    int bpr = gridDim.x >> 2;
    int rel = blockIdx.x / bpr;
    int e = (blockIdx.x - rel * bpr) * 256 + threadIdx.x;
    if (e < E) {
        int src = ep.ei[rel][e];
        int dst = ep.ei[rel][E + e];
        float w = ep.ew[rel][e];
        int pos = atomicAdd(&cursor[dst], 1);
        epack[pos] = make_int2(src, __float_as_int(w));
    }
}

// ---------------- GEMM: [M,K] x [K,256] -> bf16 [M,256] ----------------
// FUSE=true: apply graph-LN affine ((v-m)*inv*lnw[k]+lnb[k]) to A while staging.

template <int K, bool FUSE>
__global__ __launch_bounds__(256) void gemm_kernel(const float* __restrict__ A, const float* __restrict__ W,
                                                   unsigned short* __restrict__ out, int M,
                                                   const float* __restrict__ stats,
                                                   const float* __restrict__ lnw, const float* __restrict__ lnb,
                                                   float invM) {
    __shared__ float At[32 * K];
    int rowBase = blockIdx.x * 32;
    int t = threadIdx.x;
    float m = 0.f, inv = 1.f;
    if (FUSE) {
        float s = stats[0], ss = stats[1];
        m = s * invM;
        float var = ss * invM - m * m;
        inv = 1.f / (sqrtf(fmaxf(var, 0.f)) + 1e-5f);
    }
    for (int idx = t; idx < 32 * K; idx += 256) {
        int r = idx / K;
        int k = idx & (K - 1);
        int row = rowBase + r;
        float v = (row < M) ? A[(size_t)row * K + k] : 0.f;
        if (FUSE) v = (v - m) * inv * lnw[k] + lnb[k];
        At[idx] = v;
    }
    __syncthreads();
    float acc[32];
#pragma unroll
    for (int r = 0; r < 32; ++r) acc[r] = 0.f;
    int col = t;
    for (int k = 0; k < K; k += 4) {
        float w0 = W[(k + 0) * HDIM + col];
        float w1 = W[(k + 1) * HDIM + col];
        float w2 = W[(k + 2) * HDIM + col];
        float w3 = W[(k + 3) * HDIM + col];
#pragma unroll
        for (int r = 0; r < 32; ++r) {
            float4 a = *(const float4*)&At[r * K + k];
            acc[r] += a.x * w0 + a.y * w1 + a.z * w2 + a.w * w3;
        }
    }
#pragma unroll
    for (int r = 0; r < 32; ++r) {
        int row = rowBase + r;
        if (row < M) out[((size_t)row << 8) + col] = f32_to_bf16_rne(acc[r]);
    }
}

// ---------------- Aggregation: one wave per dst node, bf16 gather ----------------

__device__ inline void acc_edge(float4& acc, float w, ushort4 u) {
    acc.x += w * __uint_as_float((unsigned)u.x << 16);
    acc.y += w * __uint_as_float((unsigned)u.y << 16);
    acc.z += w * __uint_as_float((unsigned)u.z << 16);
    acc.w += w * __uint_as_float((unsigned)u.w << 16);
}

__global__ __launch_bounds__(256) void agg_kernel(const unsigned short* __restrict__ Hf,
                                                  const int* __restrict__ offs, const int* __restrict__ cnts,
                                                  const int2* __restrict__ epack,
                                                  const float* __restrict__ bias,
                                                  float* __restrict__ outp, float* __restrict__ stats, int nNodes) {
    int gwave = (blockIdx.x << 2) | (threadIdx.x >> 6);
    int lane = threadIdx.x & 63;
    int c = lane << 2;
    float4 acc = make_float4(0.f, 0.f, 0.f, 0.f);
    if (gwave < nNodes) {
        acc = *(const float4*)&bias[c];
        int start = __builtin_amdgcn_readfirstlane(offs[gwave]);
        int cnt = __builtin_amdgcn_readfirstlane(cnts[gwave]);
        const int2* ep = epack + start;
        int i = 0;
        for (; i + 8 <= cnt; i += 8) {
            int2 p0 = ep[i], p1 = ep[i + 1], p2 = ep[i + 2], p3 = ep[i + 3];
            int2 p4 = ep[i + 4], p5 = ep[i + 5], p6 = ep[i + 6], p7 = ep[i + 7];
            ushort4 u0 = *(const ushort4*)&Hf[((size_t)p0.x << 8) + c];
            ushort4 u1 = *(const ushort4*)&Hf[((size_t)p1.x << 8) + c];
            ushort4 u2 = *(const ushort4*)&Hf[((size_t)p2.x << 8) + c];
            ushort4 u3 = *(const ushort4*)&Hf[((size_t)p3.x << 8) + c];
            ushort4 u4 = *(const ushort4*)&Hf[((size_t)p4.x << 8) + c];
            ushort4 u5 = *(const ushort4*)&Hf[((size_t)p5.x << 8) + c];
            ushort4 u6 = *(const ushort4*)&Hf[((size_t)p6.x << 8) + c];
            ushort4 u7 = *(const ushort4*)&Hf[((size_t)p7.x << 8) + c];
            acc_edge(acc, __int_as_float(p0.y), u0);
            acc_edge(acc, __int_as_float(p1.y), u1);
            acc_edge(acc, __int_as_float(p2.y), u2);
            acc_edge(acc, __int_as_float(p3.y), u3);
            acc_edge(acc, __int_as_float(p4.y), u4);
            acc_edge(acc, __int_as_float(p5.y), u5);
            acc_edge(acc, __int_as_float(p6.y), u6);
            acc_edge(acc, __int_as_float(p7.y), u7);
        }
        for (; i < cnt; ++i) {
            int2 p = ep[i];
            ushort4 u = *(const ushort4*)&Hf[((size_t)p.x << 8) + c];
            acc_edge(acc, __int_as_float(p.y), u);
        }
        *(float4*)&outp[((size_t)gwave << 8) + c] = acc;
    }
    float s = acc.x + acc.y + acc.z + acc.w;
    float ss = acc.x * acc.x + acc.y * acc.y + acc.z * acc.z + acc.w * acc.w;
#pragma unroll
    for (int off = 32; off > 0; off >>= 1) {
        s += __shfl_down(s, off, 64);
        ss += __shfl_down(ss, off, 64);
    }
    __shared__ float ls[8];
    int wid = threadIdx.x >> 6;
    if (lane == 0) { ls[wid] = s; ls[4 + wid] = ss; }
    __syncthreads();
    if (threadIdx.x == 0) {
        atomicAdd(&stats[0], ls[0] + ls[1] + ls[2] + ls[3]);
        atomicAdd(&stats[1], ls[4] + ls[5] + ls[6] + ls[7]);
    }
}

// ---------------- Graph LayerNorm (elementwise, in-place, final) ----------------

__global__ __launch_bounds__(256) void ln_kernel(float* __restrict__ data, const float* __restrict__ stats,
                                                 const float* __restrict__ lw, const float* __restrict__ lb,
                                                 long long total, float invM) {
    long long i4 = (long long)blockIdx.x * 256 + threadIdx.x;
    long long idx = i4 * 4;
    if (idx >= total) return;
    float m = stats[0] * invM;
    float var = stats[1] * invM - m * m;
    float inv = 1.f / (sqrtf(fmaxf(var, 0.f)) + 1e-5f);
    float4 v = *(float4*)&data[idx];
    int c = (int)(idx & (HDIM - 1));
    float4 w = *(const float4*)&lw[c];
    float4 b = *(const float4*)&lb[c];
    v.x = (v.x - m) * inv * w.x + b.x;
    v.y = (v.y - m) * inv * w.y + b.y;
    v.z = (v.z - m) * inv * w.z + b.z;
    v.w = (v.w - m) * inv * w.w + b.w;
    *(float4*)&data[idx] = v;
}

// ---------------- launch ----------------

extern "C" void kernel_launch(void* const* d_in, const int* in_sizes, int n_in,
                              void* d_out, int out_size, void* d_ws, size_t ws_size,
                              hipStream_t stream) {
    const float* x = (const float*)d_in[0];
    EdgePtrs ep;
    ep.ei[0] = (const int*)d_in[1]; ep.ew[0] = (const float*)d_in[2];
    ep.ei[1] = (const int*)d_in[3]; ep.ew[1] = (const float*)d_in[4];
    ep.ei[2] = (const int*)d_in[5]; ep.ew[2] = (const float*)d_in[6];
    ep.ei[3] = (const int*)d_in[7]; ep.ew[3] = (const float*)d_in[8];
    const float* W1 = (const float*)d_in[9];
    const float* b1 = (const float*)d_in[10];
    const float* W2 = (const float*)d_in[11];
    const float* b2 = (const float*)d_in[12];
    const float* ln1w = (const float*)d_in[13];
    const float* ln1b = (const float*)d_in[14];
    const float* ln2w = (const float*)d_in[15];
    const float* ln2b = (const float*)d_in[16];

    const int N = in_sizes[0] / 128;  // 100000
    const int E = in_sizes[2];        // 1600000
    const size_t totE = (size_t)RELS * E;
    float* out = (float*)d_out;

    // workspace layout
    char* ws = (char*)d_ws;
    unsigned short* Hbuf = (unsigned short*)ws;     // N*256 bf16 (51.2 MB)
    int2* epack = (int2*)(Hbuf + (size_t)N * HDIM); // 4E int2 (51.2 MB)
    int* cnts = (int*)(epack + totE);               // N
    int* offs = cnts + N;                           // N
    int* cursor = offs + N;                         // N
    int* bsums = cursor + N;                        // 1024
    float* stats = (float*)(bsums + 1024);          // 4 floats

    hipMemsetAsync(cnts, 0, (size_t)N * sizeof(int), stream);
    hipMemsetAsync(stats, 0, 4 * sizeof(float), stream);

    int bpr = (E + 255) / 256;
    count_kernel<<<RELS * bpr, 256, 0, stream>>>(ep, cnts, E);
    int nb = (N + 1023) / 1024;
    scan_kernel<<<nb, 256, 0, stream>>>(cnts, offs, bsums, N);
    scan_kernel<<<1, 256, 0, stream>>>(bsums, bsums, bsums + 512, nb);
    add_off_kernel<<<(N + 255) / 256, 256, 0, stream>>>(offs, bsums, cursor, N);
    fill_kernel<<<RELS * bpr, 256, 0, stream>>>(ep, cursor, epack, E);

    long long total = (long long)N * HDIM;
    float invM = 1.f / (float)total;
    int gemmGrid = (N + 31) / 32;
    int aggGrid = (N + 3) / 4;
    int lnGrid = (int)((total / 4 + 255) / 256);

    // Layer 1: x@W1 -> Hbuf(bf16) ; agg -> d_out (+stats0)
    gemm_kernel<128, false><<<gemmGrid, 256, 0, stream>>>(x, W1, Hbuf, N, nullptr, nullptr, nullptr, invM);
    agg_kernel<<<aggGrid, 256, 0, stream>>>(Hbuf, offs, cnts, epack, b1, out, stats, N);

    // Layer 2: LN1 fused into GEMM2 staging ; agg -> d_out (+stats1) ; LN2
    gemm_kernel<256, true><<<gemmGrid, 256, 0, stream>>>(out, W2, Hbuf, N, stats, ln1w, ln1b, invM);
    agg_kernel<<<aggGrid, 256, 0, stream>>>(Hbuf, offs, cnts, epack, b2, out, stats + 2, N);
    ln_kernel<<<lnGrid, 256, 0, stream>>>(out, stats + 2, ln2w, ln2b, total, invM);
}

// Round 3
// 2687.240 us; speedup vs baseline: 1.3164x; 1.0838x over previous
//
#include <hip/hip_runtime.h>
#include <hip/hip_bf16.h>

// HeteroGNN R3:
// - agg gather is latency/MSHR-bound, not byte-bound: bucket each dst's edge
//   list by src (8192-row buckets ~ 4MB bf16 ~ per-XCD L2) via a (dst,bucket)
//   counting sort so concurrent waves sweep src-space in lockstep -> L2 hits.
// - GEMM was LDS-bound (0.25 fma/LDS-byte); 8x8 register blocking + transposed
//   padded A-tile (ds_read_b128, 2-way banks) -> ALU-bound.

#define RELS 4
#define HDIM 256
#define NB 16          // src buckets per dst (src>>13, src<100000 -> 0..12)
#define BSH 13

struct EdgePtrs {
    const int*   ei[RELS];
    const float* ew[RELS];
};

__device__ inline unsigned short f32_to_bf16_rne(float f) {
    unsigned int u = __float_as_uint(f);
    unsigned int r = 0x7FFFu + ((u >> 16) & 1u);
    return (unsigned short)((u + r) >> 16);
}

// ---------------- CSR build (keys = dst*NB + src_bucket) ----------------

__global__ __launch_bounds__(256) void count_kernel(EdgePtrs ep, int* __restrict__ cnts, int E) {
    int bpr = gridDim.x >> 2;
    int rel = blockIdx.x / bpr;
    int e = (blockIdx.x - rel * bpr) * 256 + threadIdx.x;
    if (e < E) {
        int src = ep.ei[rel][e];
        int dst = ep.ei[rel][E + e];
        atomicAdd(&cnts[(dst << 4) | (src >> BSH)], 1);
    }
}

template <int ITEMS>
__global__ __launch_bounds__(256) void scan_kernel(const int* __restrict__ in, int* __restrict__ out,
                                                   int* __restrict__ blockSums, int n) {
    __shared__ int wsum[4];
    int t = threadIdx.x;
    int base = blockIdx.x * 256 * ITEMS;
    int idx0 = base + t * ITEMS;
    int v[ITEMS];
    int local = 0;
#pragma unroll
    for (int j = 0; j < ITEMS; ++j) {
        v[j] = (idx0 + j < n) ? in[idx0 + j] : 0;
        local += v[j];
    }
    int lane = t & 63;
    int incl = local;
#pragma unroll
    for (int off = 1; off < 64; off <<= 1) {
        int y = __shfl_up(incl, off, 64);
        if (lane >= off) incl += y;
    }
    int waveId = t >> 6;
    if (lane == 63) wsum[waveId] = incl;
    __syncthreads();
    int waveOff = 0;
    for (int wi = 0; wi < waveId; ++wi) waveOff += wsum[wi];
    int run = waveOff + incl - local;
#pragma unroll
    for (int j = 0; j < ITEMS; ++j) {
        if (idx0 + j < n) out[idx0 + j] = run;
        run += v[j];
    }
    if (t == 255 && blockSums) blockSums[blockIdx.x] = waveOff + incl;
}

__global__ __launch_bounds__(256) void add_off_kernel(int* __restrict__ offs, const int* __restrict__ bsums,
                                                      int* __restrict__ cursor, int n) {
    int i = blockIdx.x * 256 + threadIdx.x;
    if (i < n) {
        int o = offs[i] + bsums[i >> 11];   // 2048 elems per L0 scan block
        offs[i] = o;
        cursor[i] = o;
    }
}

__global__ __launch_bounds__(256) void fill_kernel(EdgePtrs ep, int* __restrict__ cursor,
                                                   int2* __restrict__ epack, int E) {
    int bpr = gridDim.x >> 2;
    int rel = blockIdx.x / bpr;
    int e = (blockIdx.x - rel * bpr) * 256 + threadIdx.x;
    if (e < E) {
        int src = ep.ei[rel][e];
        int dst = ep.ei[rel][E + e];
        float w = ep.ew[rel][e];
        int pos = atomicAdd(&cursor[(dst << 4) | (src >> BSH)], 1);
        epack[pos] = make_int2(src, __float_as_int(w));
    }
}

// ---------------- GEMM: [M,K] x [K,256] -> bf16 [M,256] ----------------
// 64 rows x 256 cols per block; thread = 8 rows x 8 cols; A staged transposed
// (row-dim padded 64->68) so compute reads are ds_read_b128 with free banks.

template <int K, bool FUSE>
__global__ __launch_bounds__(256) void gemm_kernel(const float* __restrict__ A, const float* __restrict__ W,
                                                   unsigned short* __restrict__ out, int M,
                                                   const float* __restrict__ stats,
                                                   const float* __restrict__ lnw, const float* __restrict__ lnb,
                                                   float invM) {
    __shared__ float At[K * 68];
    int t = threadIdx.x;
    int rowBase = blockIdx.x * 64;
    float m = 0.f, inv = 1.f;
    if (FUSE) {
        float s = stats[0], ss = stats[1];
        m = s * invM;
        float var = ss * invM - m * m;
        inv = 1.f / (sqrtf(fmaxf(var, 0.f)) + 1e-5f);
    }
    constexpr int KQ = K / 4;
    for (int idx = t; idx < 64 * KQ; idx += 256) {
        int row = idx / KQ;
        int kq = idx - row * KQ;
        int grow = rowBase + row;
        float4 a = make_float4(0.f, 0.f, 0.f, 0.f);
        if (grow < M) a = *(const float4*)&A[(size_t)grow * K + kq * 4];
        if (FUSE) {
            float4 w4 = *(const float4*)&lnw[kq * 4];
            float4 b4 = *(const float4*)&lnb[kq * 4];
            a.x = (a.x - m) * inv * w4.x + b4.x;
            a.y = (a.y - m) * inv * w4.y + b4.y;
            a.z = (a.z - m) * inv * w4.z + b4.z;
            a.w = (a.w - m) * inv * w4.w + b4.w;
        }
        At[(kq * 4 + 0) * 68 + row] = a.x;
        At[(kq * 4 + 1) * 68 + row] = a.y;
        At[(kq * 4 + 2) * 68 + row] = a.z;
        At[(kq * 4 + 3) * 68 + row] = a.w;
    }
    __syncthreads();

    int tx = t & 31;        // col base
    int ty = t >> 5;        // row group (8 rows)
    float acc[8][8];
#pragma unroll
    for (int i = 0; i < 8; ++i)
#pragma unroll
        for (int j = 0; j < 8; ++j) acc[i][j] = 0.f;

#pragma unroll 4
    for (int k = 0; k < K; ++k) {
        float4 a0 = *(const float4*)&At[k * 68 + (ty << 3)];
        float4 a1 = *(const float4*)&At[k * 68 + (ty << 3) + 4];
        float wv[8];
#pragma unroll
        for (int j = 0; j < 8; ++j) wv[j] = W[k * HDIM + tx + (j << 5)];
#pragma unroll
        for (int j = 0; j < 8; ++j) {
            acc[0][j] += a0.x * wv[j];
            acc[1][j] += a0.y * wv[j];
            acc[2][j] += a0.z * wv[j];
            acc[3][j] += a0.w * wv[j];
            acc[4][j] += a1.x * wv[j];
            acc[5][j] += a1.y * wv[j];
            acc[6][j] += a1.z * wv[j];
            acc[7][j] += a1.w * wv[j];
        }
    }
#pragma unroll
    for (int i = 0; i < 8; ++i) {
        int row = rowBase + (ty << 3) + i;
        if (row < M) {
#pragma unroll
            for (int j = 0; j < 8; ++j)
                out[((size_t)row << 8) + tx + (j << 5)] = f32_to_bf16_rne(acc[i][j]);
        }
    }
}

// ---------------- Aggregation: one wave per dst node, bf16 gather ----------------

__device__ inline void acc_edge(float4& acc, float w, ushort4 u) {
    acc.x += w * __uint_as_float((unsigned)u.x << 16);
    acc.y += w * __uint_as_float((unsigned)u.y << 16);
    acc.z += w * __uint_as_float((unsigned)u.z << 16);
    acc.w += w * __uint_as_float((unsigned)u.w << 16);
}

__global__ __launch_bounds__(256) void agg_kernel(const unsigned short* __restrict__ Hf,
                                                  const int* __restrict__ offs,
                                                  const int2* __restrict__ epack,
                                                  const float* __restrict__ bias,
                                                  float* __restrict__ outp, float* __restrict__ stats,
                                                  int nNodes, int totE) {
    int gwave = (blockIdx.x << 2) | (threadIdx.x >> 6);
    int lane = threadIdx.x & 63;
    int c = lane << 2;
    float4 acc = make_float4(0.f, 0.f, 0.f, 0.f);
    if (gwave < nNodes) {
        acc = *(const float4*)&bias[c];
        int start = __builtin_amdgcn_readfirstlane(offs[gwave << 4]);
        int endv = (gwave + 1 < nNodes) ? offs[(gwave + 1) << 4] : totE;
        int cnt = __builtin_amdgcn_readfirstlane(endv) - start;
        const int2* ep = epack + start;
        int i = 0;
        for (; i + 8 <= cnt; i += 8) {
            int2 p0 = ep[i], p1 = ep[i + 1], p2 = ep[i + 2], p3 = ep[i + 3];
            int2 p4 = ep[i + 4], p5 = ep[i + 5], p6 = ep[i + 6], p7 = ep[i + 7];
            ushort4 u0 = *(const ushort4*)&Hf[((size_t)p0.x << 8) + c];
            ushort4 u1 = *(const ushort4*)&Hf[((size_t)p1.x << 8) + c];
            ushort4 u2 = *(const ushort4*)&Hf[((size_t)p2.x << 8) + c];
            ushort4 u3 = *(const ushort4*)&Hf[((size_t)p3.x << 8) + c];
            ushort4 u4 = *(const ushort4*)&Hf[((size_t)p4.x << 8) + c];
            ushort4 u5 = *(const ushort4*)&Hf[((size_t)p5.x << 8) + c];
            ushort4 u6 = *(const ushort4*)&Hf[((size_t)p6.x << 8) + c];
            ushort4 u7 = *(const ushort4*)&Hf[((size_t)p7.x << 8) + c];
            acc_edge(acc, __int_as_float(p0.y), u0);
            acc_edge(acc, __int_as_float(p1.y), u1);
            acc_edge(acc, __int_as_float(p2.y), u2);
            acc_edge(acc, __int_as_float(p3.y), u3);
            acc_edge(acc, __int_as_float(p4.y), u4);
            acc_edge(acc, __int_as_float(p5.y), u5);
            acc_edge(acc, __int_as_float(p6.y), u6);
            acc_edge(acc, __int_as_float(p7.y), u7);
        }
        for (; i < cnt; ++i) {
            int2 p = ep[i];
            ushort4 u = *(const ushort4*)&Hf[((size_t)p.x << 8) + c];
            acc_edge(acc, __int_as_float(p.y), u);
        }
        *(float4*)&outp[((size_t)gwave << 8) + c] = acc;
    }
    float s = acc.x + acc.y + acc.z + acc.w;
    float ss = acc.x * acc.x + acc.y * acc.y + acc.z * acc.z + acc.w * acc.w;
#pragma unroll
    for (int off = 32; off > 0; off >>= 1) {
        s += __shfl_down(s, off, 64);
        ss += __shfl_down(ss, off, 64);
    }
    __shared__ float ls[8];
    int wid = threadIdx.x >> 6;
    if (lane == 0) { ls[wid] = s; ls[4 + wid] = ss; }
    __syncthreads();
    if (threadIdx.x == 0) {
        atomicAdd(&stats[0], ls[0] + ls[1] + ls[2] + ls[3]);
        atomicAdd(&stats[1], ls[4] + ls[5] + ls[6] + ls[7]);
    }
}

// ---------------- Graph LayerNorm (elementwise, in-place, final) ----------------

__global__ __launch_bounds__(256) void ln_kernel(float* __restrict__ data, const float* __restrict__ stats,
                                                 const float* __restrict__ lw, const float* __restrict__ lb,
                                                 long long total, float invM) {
    long long i4 = (long long)blockIdx.x * 256 + threadIdx.x;
    long long idx = i4 * 4;
    if (idx >= total) return;
    float m = stats[0] * invM;
    float var = stats[1] * invM - m * m;
    float inv = 1.f / (sqrtf(fmaxf(var, 0.f)) + 1e-5f);
    float4 v = *(float4*)&data[idx];
    int c = (int)(idx & (HDIM - 1));
    float4 w = *(const float4*)&lw[c];
    float4 b = *(const float4*)&lb[c];
    v.x = (v.x - m) * inv * w.x + b.x;
    v.y = (v.y - m) * inv * w.y + b.y;
    v.z = (v.z - m) * inv * w.z + b.z;
    v.w = (v.w - m) * inv * w.w + b.w;
    *(float4*)&data[idx] = v;
}

// ---------------- launch ----------------

extern "C" void kernel_launch(void* const* d_in, const int* in_sizes, int n_in,
                              void* d_out, int out_size, void* d_ws, size_t ws_size,
                              hipStream_t stream) {
    const float* x = (const float*)d_in[0];
    EdgePtrs ep;
    ep.ei[0] = (const int*)d_in[1]; ep.ew[0] = (const float*)d_in[2];
    ep.ei[1] = (const int*)d_in[3]; ep.ew[1] = (const float*)d_in[4];
    ep.ei[2] = (const int*)d_in[5]; ep.ew[2] = (const float*)d_in[6];
    ep.ei[3] = (const int*)d_in[7]; ep.ew[3] = (const float*)d_in[8];
    const float* W1 = (const float*)d_in[9];
    const float* b1 = (const float*)d_in[10];
    const float* W2 = (const float*)d_in[11];
    const float* b2 = (const float*)d_in[12];
    const float* ln1w = (const float*)d_in[13];
    const float* ln1b = (const float*)d_in[14];
    const float* ln2w = (const float*)d_in[15];
    const float* ln2b = (const float*)d_in[16];

    const int N = in_sizes[0] / 128;  // 100000
    const int E = in_sizes[2];        // 1600000
    const int totE = RELS * E;
    const int nKeys = N * NB;         // 1.6M
    float* out = (float*)d_out;

    // workspace layout
    char* ws = (char*)d_ws;
    unsigned short* Hbuf = (unsigned short*)ws;        // N*256 bf16 (51.2 MB)
    int2* epack = (int2*)(Hbuf + (size_t)N * HDIM);    // totE int2 (51.2 MB)
    int* cnts = (int*)(epack + totE);                  // nKeys (6.4 MB)
    int* offs = cnts + nKeys;                          // nKeys
    int* cursor = offs + nKeys;                        // nKeys
    int* bsums = cursor + nKeys;                       // 1024
    float* stats = (float*)(bsums + 1024);             // 4 floats

    hipMemsetAsync(cnts, 0, (size_t)nKeys * sizeof(int), stream);
    hipMemsetAsync(stats, 0, 4 * sizeof(float), stream);

    int bpr = (E + 255) / 256;
    count_kernel<<<RELS * bpr, 256, 0, stream>>>(ep, cnts, E);
    int nb1 = (nKeys + 2047) / 2048;   // 782 L0 blocks (ITEMS=8)
    scan_kernel<8><<<nb1, 256, 0, stream>>>(cnts, offs, bsums, nKeys);
    scan_kernel<4><<<1, 256, 0, stream>>>(bsums, bsums, nullptr, nb1);
    add_off_kernel<<<(nKeys + 255) / 256, 256, 0, stream>>>(offs, bsums, cursor, nKeys);
    fill_kernel<<<RELS * bpr, 256, 0, stream>>>(ep, cursor, epack, E);

    long long total = (long long)N * HDIM;
    float invM = 1.f / (float)total;
    int gemmGrid = (N + 63) / 64;
    int aggGrid = (N + 3) / 4;
    int lnGrid = (int)((total / 4 + 255) / 256);

    // Layer 1: x@W1 -> Hbuf(bf16) ; agg -> d_out (+stats0)
    gemm_kernel<128, false><<<gemmGrid, 256, 0, stream>>>(x, W1, Hbuf, N, nullptr, nullptr, nullptr, invM);
    agg_kernel<<<aggGrid, 256, 0, stream>>>(Hbuf, offs, epack, b1, out, stats, N, totE);

    // Layer 2: LN1 fused into GEMM2 staging ; agg -> d_out (+stats1) ; LN2
    gemm_kernel<256, true><<<gemmGrid, 256, 0, stream>>>(out, W2, Hbuf, N, stats, ln1w, ln1b, invM);
    agg_kernel<<<aggGrid, 256, 0, stream>>>(Hbuf, offs, epack, b2, out, stats + 2, N, totE);
    ln_kernel<<<lnGrid, 256, 0, stream>>>(out, stats + 2, ln2w, ln2b, total, invM);
}